// Round 1
// baseline (107.993 us; speedup 1.0000x reference)
//
#include <hip/hip_runtime.h>
#include <math.h>

#define NB 8192
#define DK 256
#define BM 128
#define BK 64

typedef __bf16 bf16x8 __attribute__((ext_vector_type(8)));
typedef float f32x4 __attribute__((ext_vector_type(4)));

__device__ inline unsigned short f2bf(float f) {
  unsigned u = __float_as_uint(f);
  u += 0x7fffu + ((u >> 16) & 1u);          // round-to-nearest-even
  return (unsigned short)(u >> 16);
}

__device__ inline void gld_lds16(const void* g, void* l) {
  __builtin_amdgcn_global_load_lds(
      (const __attribute__((address_space(1))) void*)g,
      (__attribute__((address_space(3))) void*)l, 16, 0, 0);
}

// ---------------- Kernel 1: L2-normalize rows, fp32 -> bf16; zero accumulator
__global__ __launch_bounds__(256) void normalize_kernel(
    const float* __restrict__ emb, unsigned short* __restrict__ ebf,
    float* __restrict__ acc) {
  if (blockIdx.x == 0 && threadIdx.x == 0) acc[0] = 0.0f;
  int wave = threadIdx.x >> 6;
  int lane = threadIdx.x & 63;
  int row = blockIdx.x * 4 + wave;                  // one wave per row
  const float4* src = reinterpret_cast<const float4*>(emb + (size_t)row * DK) + lane;
  float4 v = *src;
  float ss = v.x * v.x + v.y * v.y + v.z * v.z + v.w * v.w;
  #pragma unroll
  for (int m = 1; m < 64; m <<= 1) ss += __shfl_xor(ss, m, 64);
  float inv = 1.0f / sqrtf(ss);
  ushort4 o;
  o.x = f2bf(v.x * inv);
  o.y = f2bf(v.y * inv);
  o.z = f2bf(v.z * inv);
  o.w = f2bf(v.w * inv);
  *reinterpret_cast<ushort4*>(ebf + (size_t)row * DK + lane * 4) = o;
}

// ---------------- Kernel 2: sim tile via bf16 MFMA + fused circle-loss epilogue
// Only upper-triangular tiles (tc >= tr); off-diagonal partials doubled.
__global__ __launch_bounds__(256) void circle_gemm(
    const unsigned short* __restrict__ ebf, const int* __restrict__ labels,
    float* __restrict__ acc) {
  int tr = blockIdx.y, tc = blockIdx.x;
  if (tc < tr) return;                               // symmetry: skip lower triangle

  __shared__ unsigned short As[BM * BK];             // swizzled storage, 16 KB
  __shared__ unsigned short Bs[BM * BK];             // 16 KB
  __shared__ int labR[BM], labC[BM];
  __shared__ float wsum[4];

  int tid = threadIdx.x;
  int lane = tid & 63;
  int wave = tid >> 6;
  int row0 = tr * BM, col0 = tc * BM;

  if (tid < 128) labR[tid] = labels[row0 + tid];
  else           labC[tid - 128] = labels[col0 + (tid - 128)];

  f32x4 accf[4][4] = {};                             // 64 fp32 accum / thread

  int wr = (wave >> 1) * 64;                         // wave's 64x64 sub-tile
  int wc = (wave & 1) * 64;

  for (int k0 = 0; k0 < DK; k0 += BK) {
    // stage A,B: 16 KB each = 4 rounds x 256 threads x 16B (global_load_lds w=16)
    // LDS dest is linear (o); global source is pre-swizzled so that
    // S[o] = data[o ^ ((row&7)<<4)]  (st-style XOR swizzle, m173 pattern)
    #pragma unroll
    for (int q = 0; q < 4; ++q) {
      int o = q * 4096 + tid * 16;                   // linear byte offset
      int r = o >> 7;                                // row (128B rows)
      int os = o ^ ((r & 7) << 4);                   // swizzled offset (same row)
      int kc = (os & 127) >> 1;                      // bf16 col within row
      gld_lds16(&ebf[(size_t)(row0 + r) * DK + k0 + kc], ((char*)As) + o);
      gld_lds16(&ebf[(size_t)(col0 + r) * DK + k0 + kc], ((char*)Bs) + o);
    }
    __syncthreads();

    #pragma unroll
    for (int kk = 0; kk < BK; kk += 32) {
      int frow = lane & 15;
      int kb = (kk + ((lane >> 4) << 3)) * 2;        // byte offset of 8-k group
      bf16x8 a[4], b[4];
      #pragma unroll
      for (int m = 0; m < 4; ++m) {
        int r = wr + m * 16 + frow;
        int ob = (r << 7) + kb;
        ob ^= (r & 7) << 4;                          // swizzled read
        a[m] = *reinterpret_cast<bf16x8*>(((char*)As) + ob);
      }
      #pragma unroll
      for (int n = 0; n < 4; ++n) {
        int r = wc + n * 16 + frow;
        int ob = (r << 7) + kb;
        ob ^= (r & 7) << 4;
        b[n] = *reinterpret_cast<bf16x8*>(((char*)Bs) + ob);
      }
      #pragma unroll
      for (int m = 0; m < 4; ++m)
        #pragma unroll
        for (int n = 0; n < 4; ++n)
          accf[m][n] = __builtin_amdgcn_mfma_f32_16x16x32_bf16(a[m], b[n], accf[m][n], 0, 0, 0);
    }
    __syncthreads();
  }

  // epilogue: circle-loss terms, one exp per element
  // C/D layout (verified m89/m91): col = lane&15, row = (lane>>4)*4 + reg
  float lsum = 0.0f;
  int rbase = wr + ((lane >> 4) << 2);
  int cbase = wc + (lane & 15);
  #pragma unroll
  for (int m = 0; m < 4; ++m) {
    #pragma unroll
    for (int n = 0; n < 4; ++n) {
      int lc = labC[cbase + n * 16];
      #pragma unroll
      for (int e = 0; e < 4; ++e) {
        float s = accf[m][n][e];
        bool pos = (labR[rbase + m * 16 + e] == lc);
        float relu = pos ? fmaxf(s - 0.75f, 0.0f) : fmaxf(0.25f - s, 0.0f);
        float arg  = pos ? (2.5f - 2.0f * s)      : (2.0f * s + 0.5f);
        lsum += relu * __expf(arg);
      }
    }
  }
  #pragma unroll
  for (int m = 32; m; m >>= 1) lsum += __shfl_xor(lsum, m, 64);
  if (lane == 0) wsum[wave] = lsum;
  __syncthreads();
  if (tid == 0) {
    float s = wsum[0] + wsum[1] + wsum[2] + wsum[3];
    if (tc != tr) s *= 2.0f;                         // symmetry doubling
    atomicAdd(acc, s);
  }
}

// ---------------- Kernel 3: finalize
__global__ void finalize_kernel(const float* __restrict__ acc, float* __restrict__ out) {
  out[0] = logf(1.0f + acc[0]);
}

extern "C" void kernel_launch(void* const* d_in, const int* in_sizes, int n_in,
                              void* d_out, int out_size, void* d_ws, size_t ws_size,
                              hipStream_t stream) {
  const float* emb = (const float*)d_in[0];
  const int* labels = (const int*)d_in[1];
  float* out = (float*)d_out;
  unsigned short* ebf = (unsigned short*)d_ws;                       // 4 MB bf16 E
  float* acc = (float*)((char*)d_ws + (size_t)NB * DK * 2);          // scalar accum

  hipLaunchKernelGGL(normalize_kernel, dim3(NB / 4), dim3(256), 0, stream, emb, ebf, acc);
  hipLaunchKernelGGL(circle_gemm, dim3(NB / BM, NB / BM), dim3(256), 0, stream, ebf, labels, acc);
  hipLaunchKernelGGL(finalize_kernel, dim3(1), dim3(1), 0, stream, acc, out);
}